// Round 6
// baseline (395.097 us; speedup 1.0000x reference)
//
#include <hip/hip_runtime.h>
#include <hip/hip_bf16.h>

typedef short s16x8 __attribute__((ext_vector_type(8)));
typedef unsigned short u16x4 __attribute__((ext_vector_type(4)));
typedef float f32x4 __attribute__((ext_vector_type(4)));

#define MFMA16(a,b,c) __builtin_amdgcn_mfma_f32_16x16x32_bf16((a),(b),(c),0,0,0)

__device__ __forceinline__ unsigned short f2bf(float x){
  unsigned int u = __float_as_uint(x);
  u += 0x7fffu + ((u >> 16) & 1u);
  return (unsigned short)(u >> 16);
}

__device__ __forceinline__ void gl_lds16(const unsigned short* g, unsigned short* l){
  __builtin_amdgcn_global_load_lds((const __attribute__((address_space(1))) unsigned int*)g,
                                   (__attribute__((address_space(3))) unsigned int*)l, 16, 0, 0);
}

// ---------------- weight prep: W[k][n] fp32 -> Wt[n][k] bf16 (LDS transpose) ----------------
__global__ void __launch_bounds__(256) wt_prep(const float* __restrict__ Wq, const float* __restrict__ Wp,
                                               unsigned short* __restrict__ WqT, unsigned short* __restrict__ WpT){
  __shared__ unsigned short tb[64][65];
  int blk = blockIdx.x;
  const float* src; unsigned short* dst; int N, k0, n0;
  if (blk < 192){
    src = Wq; dst = WqT; N = 1536;
    n0 = (blk % 24)*64; k0 = (blk / 24)*64;
  } else {
    blk -= 192; src = Wp; dst = WpT; N = 512;
    n0 = (blk & 7)*64; k0 = (blk >> 3)*64;
  }
  const int tid = threadIdx.x;
  const int nl = tid & 63;
  #pragma unroll
  for (int it = 0; it < 16; ++it){
    const int kl = it*4 + (tid >> 6);
    tb[kl][nl] = f2bf(src[(size_t)(k0+kl)*N + n0 + nl]);
  }
  __syncthreads();
  const int c2 = (tid & 31)*2;
  #pragma unroll
  for (int it = 0; it < 8; ++it){
    const int nw = it*8 + (tid >> 5);
    unsigned int v = (unsigned int)tb[c2][nw] | ((unsigned int)tb[c2+1][nw] << 16);
    *(unsigned int*)(dst + (size_t)(n0+nw)*512 + k0 + c2) = v;
  }
}

// ---------------- x (b,c,f,t) fp32 -> h [n=b*64+f][t][c] bf16 ----------------
__global__ void __launch_bounds__(256) x_to_h(const float* __restrict__ x, unsigned short* __restrict__ h){
  __shared__ unsigned short tb[64][65];
  const int blk = blockIdx.x;
  const int ttt = blk & 7, cht = (blk >> 3) & 7, n = blk >> 6;
  const int b = n >> 6, f = n & 63;
  const int t = threadIdx.x;
  const int tt0 = ttt*64, ch0 = cht*64;
  const float* xb = x + ((size_t)(b*512 + ch0)*64 + f)*512 + tt0;
  const int ttl = t & 63;
  #pragma unroll
  for (int it = 0; it < 16; ++it){
    const int chl = it*4 + (t >> 6);
    tb[chl][ttl] = f2bf(xb[(size_t)chl*32768 + ttl]);
  }
  __syncthreads();
  unsigned short* hb = h + ((size_t)n*512 + tt0)*512 + ch0;
  const int c2 = (t & 31)*2;
  #pragma unroll
  for (int it = 0; it < 8; ++it){
    const int ttw = it*8 + (t >> 5);
    unsigned int v = (unsigned int)tb[c2][ttw] | ((unsigned int)tb[c2+1][ttw] << 16);
    *(unsigned int*)(hb + (size_t)ttw*512 + c2) = v;
  }
}

// ---------------- 256x256 8-wave, BK=64, 4-phase-per-K-tile GEMM core ----------------
// A [M][512] bf16, Bt [N][512] bf16. LDS dyn 128 KiB: A0|B0|A1|B1 (32 KiB each),
// [256 rows][8 gran][8 elem], granule XOR-swizzled via pre-swizzled global src.
// Memory hand-off happens ONLY at K-tile boundaries -> __syncthreads() there.
// Intra-phase raw s_barriers only separate ops on disjoint LDS buffers
// (reads: buf[cur], staging writes: buf[cur^1]) so their lack of compiler
// memory-fencing is harmless for correctness.
__device__ __forceinline__ void gemm_core_256(const unsigned short* __restrict__ A,
                                              const unsigned short* __restrict__ Bt,
                                              char* smem, int bm, int bn, int tid,
                                              f32x4 (&acc)[8][4]){
  const int lane = tid & 63, w = tid >> 6;
  const int wm = w >> 2, wn = w & 3;
  const int lq = lane & 15, lg = lane >> 4;
  const unsigned short* Ag[4]; const unsigned short* Bg[4]; int wub[4];
  #pragma unroll
  for (int j = 0; j < 4; ++j){
    const int slot = j*512 + tid;
    const int srow = slot >> 3;
    const int sg = (slot & 7) ^ (srow & 7);
    Ag[j] = A  + (size_t)(bm*256 + srow)*512 + sg*8;
    Bg[j] = Bt + (size_t)(bn*256 + srow)*512 + sg*8;
    wub[j] = (j*512 + w*64)*8;
  }
  unsigned short* LA[2] = {(unsigned short*)smem,           (unsigned short*)(smem + 65536)};
  unsigned short* LB[2] = {(unsigned short*)(smem + 32768), (unsigned short*)(smem + 98304)};
  int raby[8], rbby[4];
  #pragma unroll
  for (int i = 0; i < 8; ++i) raby[i] = (wm*128 + i*16 + lq)*128;
  #pragma unroll
  for (int j = 0; j < 4; ++j) rbby[j] = (wn*64 + j*16 + lq)*128;
  const int cg0 = ((lg    ) ^ (lq & 7))*16;
  const int cg1 = ((4 + lg) ^ (lq & 7))*16;
  // prologue: stage K-tile 0 into buf0
  #pragma unroll
  for (int j = 0; j < 4; ++j){ gl_lds16(Ag[j], LA[0] + wub[j]); gl_lds16(Bg[j], LB[0] + wub[j]); }
  __syncthreads();
  for (int kt = 0; kt < 8; ++kt){
    const int cur = kt & 1;
    const char* Ab = (const char*)LA[cur];
    const char* Bb = (const char*)LB[cur];
    unsigned short* An = LA[cur^1]; unsigned short* Bn = LB[cur^1];
    const int nko = (kt + 1)*64;
    const bool st = (kt < 7);
    s16x8 a[4][2], b0[2][2], b1[2][2];
    // ---- P0: read A mq0 + B np0; stage A halves 0,1; MFMA quad (m0,n0)
    #pragma unroll
    for (int i = 0; i < 4; ++i){
      a[i][0] = *(const s16x8*)(Ab + raby[i] + cg0);
      a[i][1] = *(const s16x8*)(Ab + raby[i] + cg1);
    }
    #pragma unroll
    for (int j = 0; j < 2; ++j){
      b0[j][0] = *(const s16x8*)(Bb + rbby[j] + cg0);
      b0[j][1] = *(const s16x8*)(Bb + rbby[j] + cg1);
    }
    if (st){ gl_lds16(Ag[0] + nko, An + wub[0]); gl_lds16(Ag[1] + nko, An + wub[1]); }
    __builtin_amdgcn_sched_barrier(0);
    __builtin_amdgcn_s_barrier();
    __builtin_amdgcn_sched_barrier(0);
    __builtin_amdgcn_s_setprio(1);
    #pragma unroll
    for (int i = 0; i < 4; ++i)
      #pragma unroll
      for (int j = 0; j < 2; ++j){
        acc[i][j] = MFMA16(a[i][0], b0[j][0], acc[i][j]);
        acc[i][j] = MFMA16(a[i][1], b0[j][1], acc[i][j]);
      }
    __builtin_amdgcn_s_setprio(0);
    __builtin_amdgcn_sched_barrier(0);
    __builtin_amdgcn_s_barrier();
    __builtin_amdgcn_sched_barrier(0);
    // ---- P1: read B np1; stage A halves 2,3; MFMA quad (m0,n1)
    #pragma unroll
    for (int j = 0; j < 2; ++j){
      b1[j][0] = *(const s16x8*)(Bb + rbby[2+j] + cg0);
      b1[j][1] = *(const s16x8*)(Bb + rbby[2+j] + cg1);
    }
    if (st){ gl_lds16(Ag[2] + nko, An + wub[2]); gl_lds16(Ag[3] + nko, An + wub[3]); }
    __builtin_amdgcn_sched_barrier(0);
    __builtin_amdgcn_s_barrier();
    __builtin_amdgcn_sched_barrier(0);
    __builtin_amdgcn_s_setprio(1);
    #pragma unroll
    for (int i = 0; i < 4; ++i)
      #pragma unroll
      for (int j = 0; j < 2; ++j){
        acc[i][2+j] = MFMA16(a[i][0], b1[j][0], acc[i][2+j]);
        acc[i][2+j] = MFMA16(a[i][1], b1[j][1], acc[i][2+j]);
      }
    __builtin_amdgcn_s_setprio(0);
    __builtin_amdgcn_sched_barrier(0);
    __builtin_amdgcn_s_barrier();
    __builtin_amdgcn_sched_barrier(0);
    // ---- P2: read A mq1; stage B halves 0,1; MFMA quad (m1,n0)
    #pragma unroll
    for (int i = 0; i < 4; ++i){
      a[i][0] = *(const s16x8*)(Ab + raby[4+i] + cg0);
      a[i][1] = *(const s16x8*)(Ab + raby[4+i] + cg1);
    }
    if (st){ gl_lds16(Bg[0] + nko, Bn + wub[0]); gl_lds16(Bg[1] + nko, Bn + wub[1]); }
    __builtin_amdgcn_sched_barrier(0);
    __builtin_amdgcn_s_barrier();
    __builtin_amdgcn_sched_barrier(0);
    __builtin_amdgcn_s_setprio(1);
    #pragma unroll
    for (int i = 0; i < 4; ++i)
      #pragma unroll
      for (int j = 0; j < 2; ++j){
        acc[4+i][j] = MFMA16(a[i][0], b0[j][0], acc[4+i][j]);
        acc[4+i][j] = MFMA16(a[i][1], b0[j][1], acc[4+i][j]);
      }
    __builtin_amdgcn_s_setprio(0);
    __builtin_amdgcn_sched_barrier(0);
    __builtin_amdgcn_s_barrier();
    __builtin_amdgcn_sched_barrier(0);
    // ---- P3: stage B halves 2,3; MFMA quad (m1,n1); boundary hand-off
    if (st){ gl_lds16(Bg[2] + nko, Bn + wub[2]); gl_lds16(Bg[3] + nko, Bn + wub[3]); }
    __builtin_amdgcn_sched_barrier(0);
    __builtin_amdgcn_s_barrier();
    __builtin_amdgcn_sched_barrier(0);
    __builtin_amdgcn_s_setprio(1);
    #pragma unroll
    for (int i = 0; i < 4; ++i)
      #pragma unroll
      for (int j = 0; j < 2; ++j){
        acc[4+i][2+j] = MFMA16(a[i][0], b1[j][0], acc[4+i][2+j]);
        acc[4+i][2+j] = MFMA16(a[i][1], b1[j][1], acc[4+i][2+j]);
      }
    __builtin_amdgcn_s_setprio(0);
    __syncthreads();                       // boundary: drains vmcnt + real fence
  }
}

// ---------------- QKV GEMM 256: h @ WqkvT -> Q,K [nh][t][64], V^T [nh][64][t] ----------------
__global__ void __launch_bounds__(512, 2) qkv_gemm256(const unsigned short* __restrict__ h,
                                                      const unsigned short* __restrict__ WqT,
                                                      const float* __restrict__ bqkv,
                                                      unsigned short* __restrict__ Qb,
                                                      unsigned short* __restrict__ Kb,
                                                      unsigned short* __restrict__ Vt){
  extern __shared__ __align__(16) char smem[];
  const int tid = threadIdx.x;
  const int orig = blockIdx.x;                 // 1536 blocks, %8==0
  const int wg = (orig & 7)*192 + (orig >> 3); // XCD-chunked
  const int bm = wg / 6, bn = wg % 6;
  f32x4 acc[8][4] = {};
  gemm_core_256(h, WqT, smem, bm, bn, tid, acc);
  const int lane = tid & 63, w = tid >> 6;
  const int wm = w >> 2, wn = w & 3;
  const int lq = lane & 15, lg = lane >> 4;
  float bj[4];
  #pragma unroll
  for (int j = 0; j < 4; ++j) bj[j] = bqkv[bn*256 + wn*64 + j*16 + lq];
  const int n = bm >> 1, tt0 = (bm & 1)*256;
  const int sel = bn >> 1, cq0 = (bn & 1)*256;
  unsigned short* Cs = (unsigned short*)smem;   // [128][264] bf16 (264 >= 256 cols + pad)
  #pragma unroll
  for (int mh = 0; mh < 2; ++mh){
    __syncthreads();
    if (wm == mh){
      #pragma unroll
      for (int i = 0; i < 8; ++i)
        #pragma unroll
        for (int j = 0; j < 4; ++j)
          #pragma unroll
          for (int r = 0; r < 4; ++r)
            Cs[(i*16 + lg*4 + r)*264 + wn*64 + j*16 + lq] = f2bf(acc[i][j][r] + bj[j]);
    }
    __syncthreads();
    if (sel < 2){
      unsigned short* dst = (sel == 0) ? Qb : Kb;
      #pragma unroll
      for (int it = 0; it < 8; ++it){
        const int idx = it*512 + tid;
        const int rowl = idx >> 5, c8 = (idx & 31)*8;
        const int cq = cq0 + c8, head = cq >> 6, d0 = cq & 63;
        const int tg = tt0 + mh*128 + rowl;
        *(s16x8*)(dst + ((size_t)(n*8 + head)*512 + tg)*64 + d0) = *(const s16x8*)(Cs + rowl*264 + c8);
      }
    } else {
      const int col = tid >> 1;
      const int cq = cq0 + col, head = cq >> 6, d = cq & 63;
      #pragma unroll
      for (int seg = 0; seg < 8; ++seg){
        const int r0 = (tid & 1)*64 + seg*8;
        s16x8 v;
        #pragma unroll
        for (int r = 0; r < 8; ++r) v[r] = (short)Cs[(r0 + r)*264 + col];
        const int tg0 = tt0 + mh*128 + r0;
        *(s16x8*)(Vt + ((size_t)(n*8 + head)*64 + d)*512 + tg0) = v;
      }
    }
  }
}

// ---------------- proj GEMM 256: ys @ WprojT + b -> out (b,c,f,t) fp32 ----------------
__global__ void __launch_bounds__(512, 2) proj_gemm256(const unsigned short* __restrict__ ys,
                                                       const unsigned short* __restrict__ WpT,
                                                       const float* __restrict__ bproj,
                                                       float* __restrict__ out){
  extern __shared__ __align__(16) char smem[];
  const int tid = threadIdx.x;
  const int orig = blockIdx.x;                // 512 blocks
  const int wg = (orig & 7)*64 + (orig >> 3);
  const int bm = wg >> 1, bn = wg & 1;
  f32x4 acc[8][4] = {};
  gemm_core_256(ys, WpT, smem, bm, bn, tid, acc);
  const int lane = tid & 63, w = tid >> 6;
  const int wm = w >> 2, wn = w & 3;
  const int lq = lane & 15, lg = lane >> 4;
  float bj[4];
  #pragma unroll
  for (int j = 0; j < 4; ++j) bj[j] = bproj[bn*256 + wn*64 + j*16 + lq];
  const int n = bm >> 1, tt0 = (bm & 1)*256;
  const int b = n >> 6, f = n & 63;
  // BUG FIX (R3-R5 absmax 6.45): stride was 132 (<256 cols) -> rows aliased.
  // [128][256] fp32 = 131072 B = exactly the 128 KiB dynamic LDS.
  float* Csf = (float*)smem;
  #pragma unroll
  for (int mh = 0; mh < 2; ++mh){
    __syncthreads();
    if (wm == mh){
      #pragma unroll
      for (int i = 0; i < 8; ++i)
        #pragma unroll
        for (int j = 0; j < 4; ++j)
          #pragma unroll
          for (int r = 0; r < 4; ++r)
            Csf[(i*16 + lg*4 + r)*256 + wn*64 + j*16 + lq] = acc[i][j][r] + bj[j];
    }
    __syncthreads();
    const int ch = tid >> 1;
    const int chg = bn*256 + ch;
    #pragma unroll
    for (int s = 0; s < 16; ++s){
      const int r0 = (tid & 1)*64 + s*4;
      f32x4 v;
      #pragma unroll
      for (int r = 0; r < 4; ++r) v[r] = Csf[(r0 + r)*256 + ch];
      const int tg = tt0 + mh*128 + r0;
      *(f32x4*)(out + ((size_t)(b*512 + chg)*64 + f)*512 + tg) = v;
    }
  }
}

// ---------------- windowed attention: LDS-staged K/V, double-buffered ----------------
__global__ void __launch_bounds__(256) attn_kernel(const unsigned short* __restrict__ Qb,
                                                   const unsigned short* __restrict__ Kb,
                                                   const unsigned short* __restrict__ Vt,
                                                   const float* __restrict__ relb,
                                                   unsigned short* __restrict__ ys){
  __shared__ __align__(16) unsigned short KsL[2][4096];
  __shared__ __align__(16) unsigned short VsL[2][4096];
  __shared__ __align__(16) unsigned short P[4][2][16*72];
  __shared__ float biasS[128];
  const int blk = blockIdx.x;
  const int qt = blk & 3, hh = (blk >> 2) & 7, n = blk >> 5;
  const int tid = threadIdx.x, lane = tid & 63, w = tid >> 6;
  if (tid < 128) biasS[tid] = relb[hh*128 + tid];
  const int q0 = qt * 128;
  const size_t nh = (size_t)(n*8 + hh);
  const unsigned short* Kbase = Kb + nh*32768;
  const unsigned short* Vbase = Vt + nh*32768;
  const int lq = lane & 15, lg = lane >> 4;
  const int qq0 = q0 + w*32;
  s16x8 bq[2][2];
  #pragma unroll
  for (int qs = 0; qs < 2; ++qs){
    const unsigned short* Qp = Qb + (nh*512 + qq0 + qs*16 + lq)*64 + lg*8;
    bq[qs][0] = *(const s16x8*)(Qp);
    bq[qs][1] = *(const s16x8*)(Qp + 32);
  }
  int r_[2], g_[2], dsl_[2];
  #pragma unroll
  for (int j = 0; j < 2; ++j){
    const int slot = j*256 + w*64 + lane;
    r_[j] = slot >> 3;
    g_[j] = (slot & 7) ^ (r_[j] & 7);
    dsl_[j] = (j*256 + w*64) * 8;
  }
  f32x4 yacc[2][4] = {{{0.f,0.f,0.f,0.f}}};
  float m_run[2] = {-INFINITY, -INFINITY}, l_run[2] = {0.f, 0.f};
  const int first = (q0 >= 128) ? 0 : ((128 - q0 + 63) >> 6);
  int cur = 0;
  {
    const int kt0 = q0 - 128 + first*64;
    #pragma unroll
    for (int j = 0; j < 2; ++j){
      gl_lds16(Kbase + (size_t)(kt0 + r_[j])*64 + g_[j]*8, KsL[0] + dsl_[j]);
      gl_lds16(Vbase + (size_t)r_[j]*512 + kt0 + g_[j]*8,  VsL[0] + dsl_[j]);
    }
  }
  for (int kt = first; kt < 4; ++kt){
    const int kt0 = q0 - 128 + kt*64;
    __syncthreads();
    if (kt < 3){
      const int nk0 = kt0 + 64;
      #pragma unroll
      for (int j = 0; j < 2; ++j){
        gl_lds16(Kbase + (size_t)(nk0 + r_[j])*64 + g_[j]*8, KsL[cur^1] + dsl_[j]);
        gl_lds16(Vbase + (size_t)r_[j]*512 + nk0 + g_[j]*8,  VsL[cur^1] + dsl_[j]);
      }
    }
    const bool wact = (kt0 <= qq0 + 31);
    if (wact){
      s16x8 av[4][2];
      #pragma unroll
      for (int mk = 0; mk < 4; ++mk){
        const int rr = mk*16 + lq;
        const unsigned short* kp = KsL[cur] + rr*64;
        av[mk][0] = *(const s16x8*)(kp + ((lg     ) ^ (rr & 7))*8);
        av[mk][1] = *(const s16x8*)(kp + ((4 + lg ) ^ (rr & 7))*8);
      }
      float pex[2][4][4];
      #pragma unroll
      for (int qs = 0; qs < 2; ++qs){
        const int qqs = qq0 + qs*16;
        if (kt0 > qqs + 15 || kt0 + 63 < qqs - 127) continue;
        f32x4 s4[4] = {{0.f,0.f,0.f,0.f}};
        #pragma unroll
        for (int mk = 0; mk < 4; ++mk){
          s4[mk] = MFMA16(av[mk][0], bq[qs][0], s4[mk]);
          s4[mk] = MFMA16(av[mk][1], bq[qs][1], s4[mk]);
        }
        const int qg = qqs + lq;
        float pmax = -3.0e38f;
        #pragma unroll
        for (int mk = 0; mk < 4; ++mk)
          #pragma unroll
          for (int r = 0; r < 4; ++r){
            const int dist = qg - (kt0 + mk*16 + lg*4 + r);
            float xv;
            if (dist >= 0 && dist < 128) xv = s4[mk][r]*0.125f + biasS[dist];
            else                         xv = -1.0e30f;
            pex[qs][mk][r] = xv;
            pmax = fmaxf(pmax, xv);
          }
        pmax = fmaxf(pmax, __shfl_xor(pmax, 16, 64));
        pmax = fmaxf(pmax, __shfl_xor(pmax, 32, 64));
        const float m_new = fmaxf(m_run[qs], pmax);
        const float scalef = __expf(m_run[qs] - m_new);
        float psum = 0.f;
        unsigned short* Pw = P[w][qs];
        #pragma unroll
        for (int mk = 0; mk < 4; ++mk){
          u16x4 pk;
          #pragma unroll
          for (int r = 0; r < 4; ++r){
            const float pe = __expf(pex[qs][mk][r] - m_new);
            psum += pe;
            pk[r] = f2bf(pe);
          }
          *(u16x4*)(Pw + lq*72 + mk*16 + lg*4) = pk;
        }
        psum += __shfl_xor(psum, 16, 64);
        psum += __shfl_xor(psum, 32, 64);
        l_run[qs] = l_run[qs]*scalef + psum;
        m_run[qs] = m_new;
        #pragma unroll
        for (int i = 0; i < 4; ++i) yacc[qs][i] *= scalef;
      }
      s16x8 vv[4][2];
      #pragma unroll
      for (int i = 0; i < 4; ++i){
        const int rr = i*16 + lq;
        const unsigned short* vp = VsL[cur] + rr*64;
        vv[i][0] = *(const s16x8*)(vp + ((lg    ) ^ (rr & 7))*8);
        vv[i][1] = *(const s16x8*)(vp + ((4 + lg) ^ (rr & 7))*8);
      }
      #pragma unroll
      for (int qs = 0; qs < 2; ++qs){
        const int qqs = qq0 + qs*16;
        if (kt0 > qqs + 15 || kt0 + 63 < qqs - 127) continue;
        unsigned short* Pw = P[w][qs];
        #pragma unroll
        for (int ks2 = 0; ks2 < 2; ++ks2){
          s16x8 pb = *(const s16x8*)(Pw + lq*72 + ks2*32 + lg*8);
          #pragma unroll
          for (int i = 0; i < 4; ++i)
            yacc[qs][i] = MFMA16(vv[i][ks2], pb, yacc[qs][i]);
        }
      }
    }
    cur ^= 1;
  }
  #pragma unroll
  for (int qs = 0; qs < 2; ++qs){
    const float inv = 1.f / l_run[qs];
    unsigned short* yp = ys + ((size_t)n*512 + qq0 + qs*16 + lq)*512 + hh*64 + lg*4;
    #pragma unroll
    for (int i = 0; i < 4; ++i){
      u16x4 o;
      #pragma unroll
      for (int r = 0; r < 4; ++r) o[r] = f2bf(yacc[qs][i][r]*inv);
      *(u16x4*)(yp + i*16) = o;
    }
  }
}

extern "C" void kernel_launch(void* const* d_in, const int* in_sizes, int n_in,
                              void* d_out, int out_size, void* d_ws, size_t ws_size,
                              hipStream_t stream){
  const float* x     = (const float*)d_in[0];
  const float* Wqkv  = (const float*)d_in[1];
  const float* bqkv  = (const float*)d_in[2];
  const float* Wproj = (const float*)d_in[3];
  const float* bproj = (const float*)d_in[4];
  const float* relb  = (const float*)d_in[5];
  float* out = (float*)d_out;
  char* ws = (char*)d_ws;
  if (ws_size < (size_t)270532608) return;
  unsigned short* hbuf = (unsigned short*)(ws);                      // 64 MiB; reused as ys
  unsigned short* Qb   = (unsigned short*)(ws + (size_t)67108864);
  unsigned short* Kb   = (unsigned short*)(ws + (size_t)134217728);
  unsigned short* Vt   = (unsigned short*)(ws + (size_t)201326592);
  unsigned short* WqT  = (unsigned short*)(ws + (size_t)268435456);
  unsigned short* WpT  = (unsigned short*)(ws + (size_t)270008320);

  hipFuncSetAttribute(reinterpret_cast<const void*>(qkv_gemm256),
                      hipFuncAttributeMaxDynamicSharedMemorySize, 131072);
  hipFuncSetAttribute(reinterpret_cast<const void*>(proj_gemm256),
                      hipFuncAttributeMaxDynamicSharedMemorySize, 131072);

  hipLaunchKernelGGL(wt_prep,      dim3(256),  dim3(256), 0, stream, Wqkv, Wproj, WqT, WpT);
  hipLaunchKernelGGL(x_to_h,       dim3(8192), dim3(256), 0, stream, x, hbuf);
  hipLaunchKernelGGL(qkv_gemm256,  dim3(1536), dim3(512), 131072, stream, hbuf, WqT, bqkv, Qb, Kb, Vt);
  hipLaunchKernelGGL(attn_kernel,  dim3(4096), dim3(256), 0, stream, Qb, Kb, Vt, relb, hbuf);
  hipLaunchKernelGGL(proj_gemm256, dim3(512),  dim3(512), 131072, stream, hbuf, WpT, bproj, out);
}

// Round 7
// 393.428 us; speedup vs baseline: 1.0042x; 1.0042x over previous
//
#include <hip/hip_runtime.h>
#include <hip/hip_bf16.h>

typedef short s16x8 __attribute__((ext_vector_type(8)));
typedef unsigned short u16x4 __attribute__((ext_vector_type(4)));
typedef float f32x4 __attribute__((ext_vector_type(4)));

#define MFMA16(a,b,c) __builtin_amdgcn_mfma_f32_16x16x32_bf16((a),(b),(c),0,0,0)

__device__ __forceinline__ unsigned short f2bf(float x){
  unsigned int u = __float_as_uint(x);
  u += 0x7fffu + ((u >> 16) & 1u);
  return (unsigned short)(u >> 16);
}

__device__ __forceinline__ void gl_lds16(const unsigned short* g, unsigned short* l){
  __builtin_amdgcn_global_load_lds((const __attribute__((address_space(1))) unsigned int*)g,
                                   (__attribute__((address_space(3))) unsigned int*)l, 16, 0, 0);
}

// ---------------- weight prep: W[k][n] fp32 -> Wt[n][k] bf16 (LDS transpose) ----------------
__global__ void __launch_bounds__(256) wt_prep(const float* __restrict__ Wq, const float* __restrict__ Wp,
                                               unsigned short* __restrict__ WqT, unsigned short* __restrict__ WpT){
  __shared__ unsigned short tb[64][65];
  int blk = blockIdx.x;
  const float* src; unsigned short* dst; int N, k0, n0;
  if (blk < 192){
    src = Wq; dst = WqT; N = 1536;
    n0 = (blk % 24)*64; k0 = (blk / 24)*64;
  } else {
    blk -= 192; src = Wp; dst = WpT; N = 512;
    n0 = (blk & 7)*64; k0 = (blk >> 3)*64;
  }
  const int tid = threadIdx.x;
  const int nl = tid & 63;
  #pragma unroll
  for (int it = 0; it < 16; ++it){
    const int kl = it*4 + (tid >> 6);
    tb[kl][nl] = f2bf(src[(size_t)(k0+kl)*N + n0 + nl]);
  }
  __syncthreads();
  const int c2 = (tid & 31)*2;
  #pragma unroll
  for (int it = 0; it < 8; ++it){
    const int nw = it*8 + (tid >> 5);
    unsigned int v = (unsigned int)tb[c2][nw] | ((unsigned int)tb[c2+1][nw] << 16);
    *(unsigned int*)(dst + (size_t)(n0+nw)*512 + k0 + c2) = v;
  }
}

// ---------------- x (b,c,f,t) fp32 -> h [n=b*64+f][t][c] bf16 ----------------
__global__ void __launch_bounds__(256) x_to_h(const float* __restrict__ x, unsigned short* __restrict__ h){
  __shared__ unsigned short tb[64][65];
  const int blk = blockIdx.x;
  const int ttt = blk & 7, cht = (blk >> 3) & 7, n = blk >> 6;
  const int b = n >> 6, f = n & 63;
  const int t = threadIdx.x;
  const int tt0 = ttt*64, ch0 = cht*64;
  const float* xb = x + ((size_t)(b*512 + ch0)*64 + f)*512 + tt0;
  const int ttl = t & 63;
  #pragma unroll
  for (int it = 0; it < 16; ++it){
    const int chl = it*4 + (t >> 6);
    tb[chl][ttl] = f2bf(xb[(size_t)chl*32768 + ttl]);
  }
  __syncthreads();
  unsigned short* hb = h + ((size_t)n*512 + tt0)*512 + ch0;
  const int c2 = (t & 31)*2;
  #pragma unroll
  for (int it = 0; it < 8; ++it){
    const int ttw = it*8 + (t >> 5);
    unsigned int v = (unsigned int)tb[c2][ttw] | ((unsigned int)tb[c2+1][ttw] << 16);
    *(unsigned int*)(hb + (size_t)ttw*512 + c2) = v;
  }
}

// ---------------- 256x256 8-wave GEMM core, K=512, counted-vmcnt ring pipeline ----------------
// A [M][512] bf16, Bt [N][512] bf16. LDS = 4-slot ring x 32 KiB (slot = half-K-tile K=32:
// A 256x32 @+0, B 256x32 @+16KiB). 16 steps; step S consumes ring slot S&3 and stages
// slot S+3 into ring (S+3)&3 (= slot read at step S-1 -> WAR-safe after its barrier).
// vmcnt(8) at step end retires slot S+1's 4 loads, keeping 8 in flight (never 0 in loop).
// Paired-row XOR swizzle: granule G=(row&1)*4+g stored at G^( (row>>1)&7 ) within 128B
// row-pair -> ds_read_b128 is 2-way (free); staging source pre-swizzled, LDS dest linear.
__device__ __forceinline__ void gemm_core_256(const unsigned short* __restrict__ A,
                                              const unsigned short* __restrict__ Bt,
                                              char* smem, int bm, int bn, int tid,
                                              f32x4 (&acc)[8][4]){
  const int lane = tid & 63, w = tid >> 6;
  const int wm = w >> 2, wn = w & 3;
  const int lq = lane & 15, lg = lane >> 4;
  // staging source: granule u = j*512+tid -> p=u>>3, Gs=u&7, G=Gs^(p&7), row=2p+(G>>2), g=G&3
  const unsigned short* Agp[2]; const unsigned short* Bgp[2]; int wub[2];
  #pragma unroll
  for (int j = 0; j < 2; ++j){
    const int u = j*512 + tid;
    const int p = u >> 3, Gs = u & 7;
    const int G = Gs ^ (p & 7);
    const int row = p*2 + (G >> 2), g = G & 3;
    Agp[j] = A  + (size_t)(bm*256 + row)*512 + g*8;
    Bgp[j] = Bt + (size_t)(bn*256 + row)*512 + g*8;
    wub[j] = (j*512 + w*64)*8;    // wave-uniform LDS elem base (lane*16B added by HW)
  }
  unsigned short* Lbase = (unsigned short*)smem;
  const int lqh = lq >> 1;
  const int gx16 = (((lq & 1)*4 + lg) ^ lqh) * 16;   // swizzled granule byte offset
  const int wmA = wm*64;   // p-base for A reads (p = wm*64 + i*8 + lqh)
  const int wnB = wn*32;   // p-base for B reads

#define GST_ISSUE(SK) { \
    unsigned short* An_ = Lbase + ((SK)&3)*16384; \
    const int ko_ = (SK)*32; \
    gl_lds16(Agp[0] + ko_, An_ + wub[0]); \
    gl_lds16(Agp[1] + ko_, An_ + wub[1]); \
    gl_lds16(Bgp[0] + ko_, An_ + 8192 + wub[0]); \
    gl_lds16(Bgp[1] + ko_, An_ + 8192 + wub[1]); }

#define GSTEP(S, VM) { \
    if ((S) + 3 < 16) GST_ISSUE((S)+3); \
    const char* Ab_ = (const char*)(Lbase + ((S)&3)*16384); \
    const char* Bb_ = Ab_ + 16384; \
    s16x8 a_[8], b_[4]; \
    _Pragma("unroll") for (int i = 0; i < 8; ++i) \
      a_[i] = *(const s16x8*)(Ab_ + (wmA + i*8 + lqh)*128 + gx16); \
    _Pragma("unroll") for (int j = 0; j < 4; ++j) \
      b_[j] = *(const s16x8*)(Bb_ + (wnB + j*8 + lqh)*128 + gx16); \
    __builtin_amdgcn_s_setprio(1); \
    _Pragma("unroll") for (int i = 0; i < 8; ++i) \
      _Pragma("unroll") for (int j = 0; j < 4; ++j) \
        acc[i][j] = MFMA16(a_[i], b_[j], acc[i][j]); \
    __builtin_amdgcn_s_setprio(0); \
    asm volatile("s_waitcnt vmcnt(" VM ")" ::: "memory"); \
    __builtin_amdgcn_sched_barrier(0); \
    __builtin_amdgcn_s_barrier(); \
    __builtin_amdgcn_sched_barrier(0); }

  // prologue: stage slots 0,1,2; retire slot 0; barrier
  GST_ISSUE(0); GST_ISSUE(1); GST_ISSUE(2);
  asm volatile("s_waitcnt vmcnt(8)" ::: "memory");
  __builtin_amdgcn_sched_barrier(0);
  __builtin_amdgcn_s_barrier();
  __builtin_amdgcn_sched_barrier(0);
  GSTEP(0,"8");  GSTEP(1,"8");  GSTEP(2,"8");  GSTEP(3,"8");
  GSTEP(4,"8");  GSTEP(5,"8");  GSTEP(6,"8");  GSTEP(7,"8");
  GSTEP(8,"8");  GSTEP(9,"8");  GSTEP(10,"8"); GSTEP(11,"8");
  GSTEP(12,"8"); GSTEP(13,"4"); GSTEP(14,"0"); GSTEP(15,"0");
#undef GSTEP
#undef GST_ISSUE
}

// ---------------- QKV GEMM 256: h @ WqkvT -> Q,K [nh][t][64], V^T [nh][64][t] ----------------
__global__ void __launch_bounds__(512, 2) qkv_gemm256(const unsigned short* __restrict__ h,
                                                      const unsigned short* __restrict__ WqT,
                                                      const float* __restrict__ bqkv,
                                                      unsigned short* __restrict__ Qb,
                                                      unsigned short* __restrict__ Kb,
                                                      unsigned short* __restrict__ Vt){
  extern __shared__ __align__(16) char smem[];
  const int tid = threadIdx.x;
  const int orig = blockIdx.x;                 // 1536 blocks, %8==0
  const int wg = (orig & 7)*192 + (orig >> 3); // XCD-chunked
  const int bm = wg / 6, bn = wg % 6;
  f32x4 acc[8][4] = {};
  gemm_core_256(h, WqT, smem, bm, bn, tid, acc);
  const int lane = tid & 63, w = tid >> 6;
  const int wm = w >> 2, wn = w & 3;
  const int lq = lane & 15, lg = lane >> 4;
  float bj[4];
  #pragma unroll
  for (int j = 0; j < 4; ++j) bj[j] = bqkv[bn*256 + wn*64 + j*16 + lq];
  const int n = bm >> 1, tt0 = (bm & 1)*256;
  const int sel = bn >> 1, cq0 = (bn & 1)*256;
  unsigned short* Cs = (unsigned short*)smem;   // [128][264] bf16
  #pragma unroll
  for (int mh = 0; mh < 2; ++mh){
    __syncthreads();
    if (wm == mh){
      #pragma unroll
      for (int i = 0; i < 8; ++i)
        #pragma unroll
        for (int j = 0; j < 4; ++j)
          #pragma unroll
          for (int r = 0; r < 4; ++r)
            Cs[(i*16 + lg*4 + r)*264 + wn*64 + j*16 + lq] = f2bf(acc[i][j][r] + bj[j]);
    }
    __syncthreads();
    if (sel < 2){
      unsigned short* dst = (sel == 0) ? Qb : Kb;
      #pragma unroll
      for (int it = 0; it < 8; ++it){
        const int idx = it*512 + tid;
        const int rowl = idx >> 5, c8 = (idx & 31)*8;
        const int cq = cq0 + c8, head = cq >> 6, d0 = cq & 63;
        const int tg = tt0 + mh*128 + rowl;
        *(s16x8*)(dst + ((size_t)(n*8 + head)*512 + tg)*64 + d0) = *(const s16x8*)(Cs + rowl*264 + c8);
      }
    } else {
      const int col = tid >> 1;
      const int cq = cq0 + col, head = cq >> 6, d = cq & 63;
      #pragma unroll
      for (int seg = 0; seg < 8; ++seg){
        const int r0 = (tid & 1)*64 + seg*8;
        s16x8 v;
        #pragma unroll
        for (int r = 0; r < 8; ++r) v[r] = (short)Cs[(r0 + r)*264 + col];
        const int tg0 = tt0 + mh*128 + r0;
        *(s16x8*)(Vt + ((size_t)(n*8 + head)*64 + d)*512 + tg0) = v;
      }
    }
  }
}

// ---------------- proj GEMM 256: ys @ WprojT + b -> out (b,c,f,t) fp32 ----------------
__global__ void __launch_bounds__(512, 2) proj_gemm256(const unsigned short* __restrict__ ys,
                                                       const unsigned short* __restrict__ WpT,
                                                       const float* __restrict__ bproj,
                                                       float* __restrict__ out){
  extern __shared__ __align__(16) char smem[];
  const int tid = threadIdx.x;
  const int orig = blockIdx.x;                // 512 blocks
  const int wg = (orig & 7)*64 + (orig >> 3);
  const int bm = wg >> 1, bn = wg & 1;
  f32x4 acc[8][4] = {};
  gemm_core_256(ys, WpT, smem, bm, bn, tid, acc);
  const int lane = tid & 63, w = tid >> 6;
  const int wm = w >> 2, wn = w & 3;
  const int lq = lane & 15, lg = lane >> 4;
  float bj[4];
  #pragma unroll
  for (int j = 0; j < 4; ++j) bj[j] = bproj[bn*256 + wn*64 + j*16 + lq];
  const int n = bm >> 1, tt0 = (bm & 1)*256;
  const int b = n >> 6, f = n & 63;
  float* Csf = (float*)smem;                  // [128][256] fp32 = 128 KiB exactly
  #pragma unroll
  for (int mh = 0; mh < 2; ++mh){
    __syncthreads();
    if (wm == mh){
      #pragma unroll
      for (int i = 0; i < 8; ++i)
        #pragma unroll
        for (int j = 0; j < 4; ++j)
          #pragma unroll
          for (int r = 0; r < 4; ++r)
            Csf[(i*16 + lg*4 + r)*256 + wn*64 + j*16 + lq] = acc[i][j][r] + bj[j];
    }
    __syncthreads();
    const int ch = tid >> 1;
    const int chg = bn*256 + ch;
    #pragma unroll
    for (int s = 0; s < 16; ++s){
      const int r0 = (tid & 1)*64 + s*4;
      f32x4 v;
      #pragma unroll
      for (int r = 0; r < 4; ++r) v[r] = Csf[(r0 + r)*256 + ch];
      const int tg = tt0 + mh*128 + r0;
      *(f32x4*)(out + ((size_t)(b*512 + chg)*64 + f)*512 + tg) = v;
    }
  }
}

// ---------------- windowed attention: LDS-staged K/V, double-buffered ----------------
__global__ void __launch_bounds__(256) attn_kernel(const unsigned short* __restrict__ Qb,
                                                   const unsigned short* __restrict__ Kb,
                                                   const unsigned short* __restrict__ Vt,
                                                   const float* __restrict__ relb,
                                                   unsigned short* __restrict__ ys){
  __shared__ __align__(16) unsigned short KsL[2][4096];
  __shared__ __align__(16) unsigned short VsL[2][4096];
  __shared__ __align__(16) unsigned short P[4][2][16*72];
  __shared__ float biasS[128];
  const int blk = blockIdx.x;
  const int qt = blk & 3, hh = (blk >> 2) & 7, n = blk >> 5;
  const int tid = threadIdx.x, lane = tid & 63, w = tid >> 6;
  if (tid < 128) biasS[tid] = relb[hh*128 + tid];
  const int q0 = qt * 128;
  const size_t nh = (size_t)(n*8 + hh);
  const unsigned short* Kbase = Kb + nh*32768;
  const unsigned short* Vbase = Vt + nh*32768;
  const int lq = lane & 15, lg = lane >> 4;
  const int qq0 = q0 + w*32;
  s16x8 bq[2][2];
  #pragma unroll
  for (int qs = 0; qs < 2; ++qs){
    const unsigned short* Qp = Qb + (nh*512 + qq0 + qs*16 + lq)*64 + lg*8;
    bq[qs][0] = *(const s16x8*)(Qp);
    bq[qs][1] = *(const s16x8*)(Qp + 32);
  }
  int r_[2], g_[2], dsl_[2];
  #pragma unroll
  for (int j = 0; j < 2; ++j){
    const int slot = j*256 + w*64 + lane;
    r_[j] = slot >> 3;
    g_[j] = (slot & 7) ^ (r_[j] & 7);
    dsl_[j] = (j*256 + w*64) * 8;
  }
  f32x4 yacc[2][4] = {{{0.f,0.f,0.f,0.f}}};
  float m_run[2] = {-INFINITY, -INFINITY}, l_run[2] = {0.f, 0.f};
  const int first = (q0 >= 128) ? 0 : ((128 - q0 + 63) >> 6);
  int cur = 0;
  {
    const int kt0 = q0 - 128 + first*64;
    #pragma unroll
    for (int j = 0; j < 2; ++j){
      gl_lds16(Kbase + (size_t)(kt0 + r_[j])*64 + g_[j]*8, KsL[0] + dsl_[j]);
      gl_lds16(Vbase + (size_t)r_[j]*512 + kt0 + g_[j]*8,  VsL[0] + dsl_[j]);
    }
  }
  for (int kt = first; kt < 4; ++kt){
    const int kt0 = q0 - 128 + kt*64;
    __syncthreads();
    if (kt < 3){
      const int nk0 = kt0 + 64;
      #pragma unroll
      for (int j = 0; j < 2; ++j){
        gl_lds16(Kbase + (size_t)(nk0 + r_[j])*64 + g_[j]*8, KsL[cur^1] + dsl_[j]);
        gl_lds16(Vbase + (size_t)r_[j]*512 + nk0 + g_[j]*8,  VsL[cur^1] + dsl_[j]);
      }
    }
    const bool wact = (kt0 <= qq0 + 31);
    if (wact){
      s16x8 av[4][2];
      #pragma unroll
      for (int mk = 0; mk < 4; ++mk){
        const int rr = mk*16 + lq;
        const unsigned short* kp = KsL[cur] + rr*64;
        av[mk][0] = *(const s16x8*)(kp + ((lg     ) ^ (rr & 7))*8);
        av[mk][1] = *(const s16x8*)(kp + ((4 + lg ) ^ (rr & 7))*8);
      }
      float pex[2][4][4];
      #pragma unroll
      for (int qs = 0; qs < 2; ++qs){
        const int qqs = qq0 + qs*16;
        if (kt0 > qqs + 15 || kt0 + 63 < qqs - 127) continue;
        f32x4 s4[4] = {{0.f,0.f,0.f,0.f}};
        #pragma unroll
        for (int mk = 0; mk < 4; ++mk){
          s4[mk] = MFMA16(av[mk][0], bq[qs][0], s4[mk]);
          s4[mk] = MFMA16(av[mk][1], bq[qs][1], s4[mk]);
        }
        const int qg = qqs + lq;
        float pmax = -3.0e38f;
        #pragma unroll
        for (int mk = 0; mk < 4; ++mk)
          #pragma unroll
          for (int r = 0; r < 4; ++r){
            const int dist = qg - (kt0 + mk*16 + lg*4 + r);
            float xv;
            if (dist >= 0 && dist < 128) xv = s4[mk][r]*0.125f + biasS[dist];
            else                         xv = -1.0e30f;
            pex[qs][mk][r] = xv;
            pmax = fmaxf(pmax, xv);
          }
        pmax = fmaxf(pmax, __shfl_xor(pmax, 16, 64));
        pmax = fmaxf(pmax, __shfl_xor(pmax, 32, 64));
        const float m_new = fmaxf(m_run[qs], pmax);
        const float scalef = __expf(m_run[qs] - m_new);
        float psum = 0.f;
        unsigned short* Pw = P[w][qs];
        #pragma unroll
        for (int mk = 0; mk < 4; ++mk){
          u16x4 pk;
          #pragma unroll
          for (int r = 0; r < 4; ++r){
            const float pe = __expf(pex[qs][mk][r] - m_new);
            psum += pe;
            pk[r] = f2bf(pe);
          }
          *(u16x4*)(Pw + lq*72 + mk*16 + lg*4) = pk;
        }
        psum += __shfl_xor(psum, 16, 64);
        psum += __shfl_xor(psum, 32, 64);
        l_run[qs] = l_run[qs]*scalef + psum;
        m_run[qs] = m_new;
        #pragma unroll
        for (int i = 0; i < 4; ++i) yacc[qs][i] *= scalef;
      }
      s16x8 vv[4][2];
      #pragma unroll
      for (int i = 0; i < 4; ++i){
        const int rr = i*16 + lq;
        const unsigned short* vp = VsL[cur] + rr*64;
        vv[i][0] = *(const s16x8*)(vp + ((lg    ) ^ (rr & 7))*8);
        vv[i][1] = *(const s16x8*)(vp + ((4 + lg) ^ (rr & 7))*8);
      }
      #pragma unroll
      for (int qs = 0; qs < 2; ++qs){
        const int qqs = qq0 + qs*16;
        if (kt0 > qqs + 15 || kt0 + 63 < qqs - 127) continue;
        unsigned short* Pw = P[w][qs];
        #pragma unroll
        for (int ks2 = 0; ks2 < 2; ++ks2){
          s16x8 pb = *(const s16x8*)(Pw + lq*72 + ks2*32 + lg*8);
          #pragma unroll
          for (int i = 0; i < 4; ++i)
            yacc[qs][i] = MFMA16(vv[i][ks2], pb, yacc[qs][i]);
        }
      }
    }
    cur ^= 1;
  }
  #pragma unroll
  for (int qs = 0; qs < 2; ++qs){
    const float inv = 1.f / l_run[qs];
    unsigned short* yp = ys + ((size_t)n*512 + qq0 + qs*16 + lq)*512 + hh*64 + lg*4;
    #pragma unroll
    for (int i = 0; i < 4; ++i){
      u16x4 o;
      #pragma unroll
      for (int r = 0; r < 4; ++r) o[r] = f2bf(yacc[qs][i][r]*inv);
      *(u16x4*)(yp + i*16) = o;
    }
  }
}

extern "C" void kernel_launch(void* const* d_in, const int* in_sizes, int n_in,
                              void* d_out, int out_size, void* d_ws, size_t ws_size,
                              hipStream_t stream){
  const float* x     = (const float*)d_in[0];
  const float* Wqkv  = (const float*)d_in[1];
  const float* bqkv  = (const float*)d_in[2];
  const float* Wproj = (const float*)d_in[3];
  const float* bproj = (const float*)d_in[4];
  const float* relb  = (const float*)d_in[5];
  float* out = (float*)d_out;
  char* ws = (char*)d_ws;
  if (ws_size < (size_t)270532608) return;
  unsigned short* hbuf = (unsigned short*)(ws);                      // 64 MiB; reused as ys
  unsigned short* Qb   = (unsigned short*)(ws + (size_t)67108864);
  unsigned short* Kb   = (unsigned short*)(ws + (size_t)134217728);
  unsigned short* Vt   = (unsigned short*)(ws + (size_t)201326592);
  unsigned short* WqT  = (unsigned short*)(ws + (size_t)268435456);
  unsigned short* WpT  = (unsigned short*)(ws + (size_t)270008320);

  hipFuncSetAttribute(reinterpret_cast<const void*>(qkv_gemm256),
                      hipFuncAttributeMaxDynamicSharedMemorySize, 131072);
  hipFuncSetAttribute(reinterpret_cast<const void*>(proj_gemm256),
                      hipFuncAttributeMaxDynamicSharedMemorySize, 131072);

  hipLaunchKernelGGL(wt_prep,      dim3(256),  dim3(256), 0, stream, Wqkv, Wproj, WqT, WpT);
  hipLaunchKernelGGL(x_to_h,       dim3(8192), dim3(256), 0, stream, x, hbuf);
  hipLaunchKernelGGL(qkv_gemm256,  dim3(1536), dim3(512), 131072, stream, hbuf, WqT, bqkv, Qb, Kb, Vt);
  hipLaunchKernelGGL(attn_kernel,  dim3(4096), dim3(256), 0, stream, Qb, Kb, Vt, relb, hbuf);
  hipLaunchKernelGGL(proj_gemm256, dim3(512),  dim3(512), 131072, stream, hbuf, WpT, bproj, out);
}

// Round 8
// 389.264 us; speedup vs baseline: 1.0150x; 1.0107x over previous
//
#include <hip/hip_runtime.h>
#include <hip/hip_bf16.h>

typedef short s16x8 __attribute__((ext_vector_type(8)));
typedef unsigned short u16x4 __attribute__((ext_vector_type(4)));
typedef float f32x4 __attribute__((ext_vector_type(4)));

#define MFMA16(a,b,c) __builtin_amdgcn_mfma_f32_16x16x32_bf16((a),(b),(c),0,0,0)

__device__ __forceinline__ unsigned short f2bf(float x){
  unsigned int u = __float_as_uint(x);
  u += 0x7fffu + ((u >> 16) & 1u);
  return (unsigned short)(u >> 16);
}

__device__ __forceinline__ void gl_lds16(const unsigned short* g, unsigned short* l){
  __builtin_amdgcn_global_load_lds((const __attribute__((address_space(1))) unsigned int*)g,
                                   (__attribute__((address_space(3))) unsigned int*)l, 16, 0, 0);
}

// ---------------- weight prep: W[k][n] fp32 -> Wt[n][k] bf16 (LDS transpose) ----------------
__global__ void __launch_bounds__(256) wt_prep(const float* __restrict__ Wq, const float* __restrict__ Wp,
                                               unsigned short* __restrict__ WqT, unsigned short* __restrict__ WpT){
  __shared__ unsigned short tb[64][65];
  int blk = blockIdx.x;
  const float* src; unsigned short* dst; int N, k0, n0;
  if (blk < 192){
    src = Wq; dst = WqT; N = 1536;
    n0 = (blk % 24)*64; k0 = (blk / 24)*64;
  } else {
    blk -= 192; src = Wp; dst = WpT; N = 512;
    n0 = (blk & 7)*64; k0 = (blk >> 3)*64;
  }
  const int tid = threadIdx.x;
  const int nl = tid & 63;
  #pragma unroll
  for (int it = 0; it < 16; ++it){
    const int kl = it*4 + (tid >> 6);
    tb[kl][nl] = f2bf(src[(size_t)(k0+kl)*N + n0 + nl]);
  }
  __syncthreads();
  const int c2 = (tid & 31)*2;
  #pragma unroll
  for (int it = 0; it < 8; ++it){
    const int nw = it*8 + (tid >> 5);
    unsigned int v = (unsigned int)tb[c2][nw] | ((unsigned int)tb[c2+1][nw] << 16);
    *(unsigned int*)(dst + (size_t)(n0+nw)*512 + k0 + c2) = v;
  }
}

// ---------------- x (b,c,f,t) fp32 -> h [n=b*64+f][t][c] bf16 ----------------
__global__ void __launch_bounds__(256) x_to_h(const float* __restrict__ x, unsigned short* __restrict__ h){
  __shared__ unsigned short tb[64][65];
  const int blk = blockIdx.x;
  const int ttt = blk & 7, cht = (blk >> 3) & 7, n = blk >> 6;
  const int b = n >> 6, f = n & 63;
  const int t = threadIdx.x;
  const int tt0 = ttt*64, ch0 = cht*64;
  const float* xb = x + ((size_t)(b*512 + ch0)*64 + f)*512 + tt0;
  const int ttl = t & 63;
  #pragma unroll
  for (int it = 0; it < 16; ++it){
    const int chl = it*4 + (t >> 6);
    tb[chl][ttl] = f2bf(xb[(size_t)chl*32768 + ttl]);
  }
  __syncthreads();
  unsigned short* hb = h + ((size_t)n*512 + tt0)*512 + ch0;
  const int c2 = (t & 31)*2;
  #pragma unroll
  for (int it = 0; it < 8; ++it){
    const int ttw = it*8 + (t >> 5);
    unsigned int v = (unsigned int)tb[c2][ttw] | ((unsigned int)tb[c2+1][ttw] << 16);
    *(unsigned int*)(hb + (size_t)ttw*512 + c2) = v;
  }
}

// ---------------- 256x256 8-wave GEMM core, K=512, ring + REGISTER-PREFETCHED reads ----------
// A [M][512] bf16, Bt [N][512] bf16. LDS = 4-slot ring x 32 KiB (slot = K=32 half-tile:
// A 256x32 @+0, B 256x32 @+16KiB). 16 steps; step S: {issue stage slot S+3;
// ds_read frags[S+1] into the ALTERNATE register set (independent of this step's MFMAs);
// MFMA frags[S] (registers loaded LAST step -> no lgkm wait on the critical path);
// vmcnt(4); s_barrier}. Publication ledger: slot k retired by vmcnt(4) at end of step
// k-2, published by that barrier, read at step k-1, consumed (MFMA) at step k,
// overwritten (stage) at step k+2 -- two barriers after last read. Race-free.
__device__ __forceinline__ void gemm_core_256(const unsigned short* __restrict__ A,
                                              const unsigned short* __restrict__ Bt,
                                              char* smem, int bm, int bn, int tid,
                                              f32x4 (&acc)[8][4]){
  const int lane = tid & 63, w = tid >> 6;
  const int wm = w >> 2, wn = w & 3;
  const int lq = lane & 15, lg = lane >> 4;
  // staging source: granule u = j*512+tid -> p=u>>3, Gs=u&7, G=Gs^(p&7), row=2p+(G>>2), g=G&3
  const unsigned short* Agp[2]; const unsigned short* Bgp[2]; int wub[2];
  #pragma unroll
  for (int j = 0; j < 2; ++j){
    const int u = j*512 + tid;
    const int p = u >> 3, Gs = u & 7;
    const int G = Gs ^ (p & 7);
    const int row = p*2 + (G >> 2), g = G & 3;
    Agp[j] = A  + (size_t)(bm*256 + row)*512 + g*8;
    Bgp[j] = Bt + (size_t)(bn*256 + row)*512 + g*8;
    wub[j] = (j*512 + w*64)*8;    // wave-uniform LDS elem base (lane*16B added by HW)
  }
  unsigned short* Lbase = (unsigned short*)smem;
  const int lqh = lq >> 1;
  const int gx16 = (((lq & 1)*4 + lg) ^ lqh) * 16;   // swizzled granule byte offset
  const int wmA = wm*64;   // p-base for A reads
  const int wnB = wn*32;   // p-base for B reads
  s16x8 aX[8], bX[4], aY[8], bY[4];

#define GST_ISSUE(SK) { \
    unsigned short* An_ = Lbase + ((SK)&3)*16384; \
    const int ko_ = (SK)*32; \
    gl_lds16(Agp[0] + ko_, An_ + wub[0]); \
    gl_lds16(Agp[1] + ko_, An_ + wub[1]); \
    gl_lds16(Bgp[0] + ko_, An_ + 8192 + wub[0]); \
    gl_lds16(Bgp[1] + ko_, An_ + 8192 + wub[1]); }

#define LDS_READ(S, AV, BV) { \
    const char* Ab_ = (const char*)(Lbase + ((S)&3)*16384); \
    const char* Bb_ = Ab_ + 16384; \
    _Pragma("unroll") for (int i = 0; i < 8; ++i) \
      AV[i] = *(const s16x8*)(Ab_ + (wmA + i*8 + lqh)*128 + gx16); \
    _Pragma("unroll") for (int j = 0; j < 4; ++j) \
      BV[j] = *(const s16x8*)(Bb_ + (wnB + j*8 + lqh)*128 + gx16); }

#define BOUND(VM) { \
    asm volatile("s_waitcnt vmcnt(" VM ")" ::: "memory"); \
    __builtin_amdgcn_sched_barrier(0); \
    __builtin_amdgcn_s_barrier(); \
    __builtin_amdgcn_sched_barrier(0); }

#define STEP(S, CA, CB, NA, NB, VM) { \
    if ((S) + 3 < 16) GST_ISSUE((S)+3); \
    if ((S) + 1 < 16) LDS_READ((S)+1, NA, NB); \
    __builtin_amdgcn_s_setprio(1); \
    _Pragma("unroll") for (int i = 0; i < 8; ++i) \
      _Pragma("unroll") for (int j = 0; j < 4; ++j) \
        acc[i][j] = MFMA16(CA[i], CB[j], acc[i][j]); \
    __builtin_amdgcn_s_setprio(0); \
    BOUND(VM); }

  // prologue: stage slots 0,1,2; retire 0,1; publish; read frags[0]
  GST_ISSUE(0); GST_ISSUE(1); GST_ISSUE(2);
  asm volatile("s_waitcnt vmcnt(4)" ::: "memory");
  __builtin_amdgcn_sched_barrier(0);
  __builtin_amdgcn_s_barrier();
  __builtin_amdgcn_sched_barrier(0);
  LDS_READ(0, aX, bX);
  // steps: even consume X / prefetch Y, odd consume Y / prefetch X
  STEP(0,  aX, bX, aY, bY, "4");  STEP(1,  aY, bY, aX, bX, "4");
  STEP(2,  aX, bX, aY, bY, "4");  STEP(3,  aY, bY, aX, bX, "4");
  STEP(4,  aX, bX, aY, bY, "4");  STEP(5,  aY, bY, aX, bX, "4");
  STEP(6,  aX, bX, aY, bY, "4");  STEP(7,  aY, bY, aX, bX, "4");
  STEP(8,  aX, bX, aY, bY, "4");  STEP(9,  aY, bY, aX, bX, "4");
  STEP(10, aX, bX, aY, bY, "4");  STEP(11, aY, bY, aX, bX, "4");
  STEP(12, aX, bX, aY, bY, "4");  STEP(13, aY, bY, aX, bX, "0");
  STEP(14, aX, bX, aY, bY, "0");  STEP(15, aY, bY, aX, bX, "0");
#undef STEP
#undef BOUND
#undef LDS_READ
#undef GST_ISSUE
}

// ---------------- QKV GEMM 256: h @ WqkvT -> Q,K [nh][t][64], V^T [nh][64][t] ----------------
__global__ void __launch_bounds__(512, 2) qkv_gemm256(const unsigned short* __restrict__ h,
                                                      const unsigned short* __restrict__ WqT,
                                                      const float* __restrict__ bqkv,
                                                      unsigned short* __restrict__ Qb,
                                                      unsigned short* __restrict__ Kb,
                                                      unsigned short* __restrict__ Vt){
  extern __shared__ __align__(16) char smem[];
  const int tid = threadIdx.x;
  const int orig = blockIdx.x;                 // 1536 blocks, %8==0
  const int wg = (orig & 7)*192 + (orig >> 3); // XCD-chunked
  const int bm = wg / 6, bn = wg % 6;
  f32x4 acc[8][4] = {};
  gemm_core_256(h, WqT, smem, bm, bn, tid, acc);
  const int lane = tid & 63, w = tid >> 6;
  const int wm = w >> 2, wn = w & 3;
  const int lq = lane & 15, lg = lane >> 4;
  float bj[4];
  #pragma unroll
  for (int j = 0; j < 4; ++j) bj[j] = bqkv[bn*256 + wn*64 + j*16 + lq];
  const int n = bm >> 1, tt0 = (bm & 1)*256;
  const int sel = bn >> 1, cq0 = (bn & 1)*256;
  unsigned short* Cs = (unsigned short*)smem;   // [128][264] bf16
  #pragma unroll
  for (int mh = 0; mh < 2; ++mh){
    __syncthreads();
    if (wm == mh){
      #pragma unroll
      for (int i = 0; i < 8; ++i)
        #pragma unroll
        for (int j = 0; j < 4; ++j)
          #pragma unroll
          for (int r = 0; r < 4; ++r)
            Cs[(i*16 + lg*4 + r)*264 + wn*64 + j*16 + lq] = f2bf(acc[i][j][r] + bj[j]);
    }
    __syncthreads();
    if (sel < 2){
      unsigned short* dst = (sel == 0) ? Qb : Kb;
      #pragma unroll
      for (int it = 0; it < 8; ++it){
        const int idx = it*512 + tid;
        const int rowl = idx >> 5, c8 = (idx & 31)*8;
        const int cq = cq0 + c8, head = cq >> 6, d0 = cq & 63;
        const int tg = tt0 + mh*128 + rowl;
        *(s16x8*)(dst + ((size_t)(n*8 + head)*512 + tg)*64 + d0) = *(const s16x8*)(Cs + rowl*264 + c8);
      }
    } else {
      const int col = tid >> 1;
      const int cq = cq0 + col, head = cq >> 6, d = cq & 63;
      #pragma unroll
      for (int seg = 0; seg < 8; ++seg){
        const int r0 = (tid & 1)*64 + seg*8;
        s16x8 v;
        #pragma unroll
        for (int r = 0; r < 8; ++r) v[r] = (short)Cs[(r0 + r)*264 + col];
        const int tg0 = tt0 + mh*128 + r0;
        *(s16x8*)(Vt + ((size_t)(n*8 + head)*64 + d)*512 + tg0) = v;
      }
    }
  }
}

// ---------------- proj GEMM 256: ys @ WprojT + b -> out (b,c,f,t) fp32 ----------------
__global__ void __launch_bounds__(512, 2) proj_gemm256(const unsigned short* __restrict__ ys,
                                                       const unsigned short* __restrict__ WpT,
                                                       const float* __restrict__ bproj,
                                                       float* __restrict__ out){
  extern __shared__ __align__(16) char smem[];
  const int tid = threadIdx.x;
  const int orig = blockIdx.x;                // 512 blocks
  const int wg = (orig & 7)*64 + (orig >> 3);
  const int bm = wg >> 1, bn = wg & 1;
  f32x4 acc[8][4] = {};
  gemm_core_256(ys, WpT, smem, bm, bn, tid, acc);
  const int lane = tid & 63, w = tid >> 6;
  const int wm = w >> 2, wn = w & 3;
  const int lq = lane & 15, lg = lane >> 4;
  float bj[4];
  #pragma unroll
  for (int j = 0; j < 4; ++j) bj[j] = bproj[bn*256 + wn*64 + j*16 + lq];
  const int n = bm >> 1, tt0 = (bm & 1)*256;
  const int b = n >> 6, f = n & 63;
  float* Csf = (float*)smem;                  // [128][256] fp32 = 128 KiB exactly
  #pragma unroll
  for (int mh = 0; mh < 2; ++mh){
    __syncthreads();
    if (wm == mh){
      #pragma unroll
      for (int i = 0; i < 8; ++i)
        #pragma unroll
        for (int j = 0; j < 4; ++j)
          #pragma unroll
          for (int r = 0; r < 4; ++r)
            Csf[(i*16 + lg*4 + r)*256 + wn*64 + j*16 + lq] = acc[i][j][r] + bj[j];
    }
    __syncthreads();
    const int ch = tid >> 1;
    const int chg = bn*256 + ch;
    #pragma unroll
    for (int s = 0; s < 16; ++s){
      const int r0 = (tid & 1)*64 + s*4;
      f32x4 v;
      #pragma unroll
      for (int r = 0; r < 4; ++r) v[r] = Csf[(r0 + r)*256 + ch];
      const int tg = tt0 + mh*128 + r0;
      *(f32x4*)(out + ((size_t)(b*512 + chg)*64 + f)*512 + tg) = v;
    }
  }
}

// ---------------- windowed attention: LDS-staged K/V, double-buffered ----------------
__global__ void __launch_bounds__(256) attn_kernel(const unsigned short* __restrict__ Qb,
                                                   const unsigned short* __restrict__ Kb,
                                                   const unsigned short* __restrict__ Vt,
                                                   const float* __restrict__ relb,
                                                   unsigned short* __restrict__ ys){
  __shared__ __align__(16) unsigned short KsL[2][4096];
  __shared__ __align__(16) unsigned short VsL[2][4096];
  __shared__ __align__(16) unsigned short P[4][2][16*72];
  __shared__ float biasS[128];
  const int blk = blockIdx.x;
  const int qt = blk & 3, hh = (blk >> 2) & 7, n = blk >> 5;
  const int tid = threadIdx.x, lane = tid & 63, w = tid >> 6;
  if (tid < 128) biasS[tid] = relb[hh*128 + tid];
  const int q0 = qt * 128;
  const size_t nh = (size_t)(n*8 + hh);
  const unsigned short* Kbase = Kb + nh*32768;
  const unsigned short* Vbase = Vt + nh*32768;
  const int lq = lane & 15, lg = lane >> 4;
  const int qq0 = q0 + w*32;
  s16x8 bq[2][2];
  #pragma unroll
  for (int qs = 0; qs < 2; ++qs){
    const unsigned short* Qp = Qb + (nh*512 + qq0 + qs*16 + lq)*64 + lg*8;
    bq[qs][0] = *(const s16x8*)(Qp);
    bq[qs][1] = *(const s16x8*)(Qp + 32);
  }
  int r_[2], g_[2], dsl_[2];
  #pragma unroll
  for (int j = 0; j < 2; ++j){
    const int slot = j*256 + w*64 + lane;
    r_[j] = slot >> 3;
    g_[j] = (slot & 7) ^ (r_[j] & 7);
    dsl_[j] = (j*256 + w*64) * 8;
  }
  f32x4 yacc[2][4] = {{{0.f,0.f,0.f,0.f}}};
  float m_run[2] = {-INFINITY, -INFINITY}, l_run[2] = {0.f, 0.f};
  const int first = (q0 >= 128) ? 0 : ((128 - q0 + 63) >> 6);
  int cur = 0;
  {
    const int kt0 = q0 - 128 + first*64;
    #pragma unroll
    for (int j = 0; j < 2; ++j){
      gl_lds16(Kbase + (size_t)(kt0 + r_[j])*64 + g_[j]*8, KsL[0] + dsl_[j]);
      gl_lds16(Vbase + (size_t)r_[j]*512 + kt0 + g_[j]*8,  VsL[0] + dsl_[j]);
    }
  }
  for (int kt = first; kt < 4; ++kt){
    const int kt0 = q0 - 128 + kt*64;
    __syncthreads();
    if (kt < 3){
      const int nk0 = kt0 + 64;
      #pragma unroll
      for (int j = 0; j < 2; ++j){
        gl_lds16(Kbase + (size_t)(nk0 + r_[j])*64 + g_[j]*8, KsL[cur^1] + dsl_[j]);
        gl_lds16(Vbase + (size_t)r_[j]*512 + nk0 + g_[j]*8,  VsL[cur^1] + dsl_[j]);
      }
    }
    const bool wact = (kt0 <= qq0 + 31);
    if (wact){
      s16x8 av[4][2];
      #pragma unroll
      for (int mk = 0; mk < 4; ++mk){
        const int rr = mk*16 + lq;
        const unsigned short* kp = KsL[cur] + rr*64;
        av[mk][0] = *(const s16x8*)(kp + ((lg     ) ^ (rr & 7))*8);
        av[mk][1] = *(const s16x8*)(kp + ((4 + lg ) ^ (rr & 7))*8);
      }
      float pex[2][4][4];
      #pragma unroll
      for (int qs = 0; qs < 2; ++qs){
        const int qqs = qq0 + qs*16;
        if (kt0 > qqs + 15 || kt0 + 63 < qqs - 127) continue;
        f32x4 s4[4] = {{0.f,0.f,0.f,0.f}};
        #pragma unroll
        for (int mk = 0; mk < 4; ++mk){
          s4[mk] = MFMA16(av[mk][0], bq[qs][0], s4[mk]);
          s4[mk] = MFMA16(av[mk][1], bq[qs][1], s4[mk]);
        }
        const int qg = qqs + lq;
        float pmax = -3.0e38f;
        #pragma unroll
        for (int mk = 0; mk < 4; ++mk)
          #pragma unroll
          for (int r = 0; r < 4; ++r){
            const int dist = qg - (kt0 + mk*16 + lg*4 + r);
            float xv;
            if (dist >= 0 && dist < 128) xv = s4[mk][r]*0.125f + biasS[dist];
            else                         xv = -1.0e30f;
            pex[qs][mk][r] = xv;
            pmax = fmaxf(pmax, xv);
          }
        pmax = fmaxf(pmax, __shfl_xor(pmax, 16, 64));
        pmax = fmaxf(pmax, __shfl_xor(pmax, 32, 64));
        const float m_new = fmaxf(m_run[qs], pmax);
        const float scalef = __expf(m_run[qs] - m_new);
        float psum = 0.f;
        unsigned short* Pw = P[w][qs];
        #pragma unroll
        for (int mk = 0; mk < 4; ++mk){
          u16x4 pk;
          #pragma unroll
          for (int r = 0; r < 4; ++r){
            const float pe = __expf(pex[qs][mk][r] - m_new);
            psum += pe;
            pk[r] = f2bf(pe);
          }
          *(u16x4*)(Pw + lq*72 + mk*16 + lg*4) = pk;
        }
        psum += __shfl_xor(psum, 16, 64);
        psum += __shfl_xor(psum, 32, 64);
        l_run[qs] = l_run[qs]*scalef + psum;
        m_run[qs] = m_new;
        #pragma unroll
        for (int i = 0; i < 4; ++i) yacc[qs][i] *= scalef;
      }
      s16x8 vv[4][2];
      #pragma unroll
      for (int i = 0; i < 4; ++i){
        const int rr = i*16 + lq;
        const unsigned short* vp = VsL[cur] + rr*64;
        vv[i][0] = *(const s16x8*)(vp + ((lg    ) ^ (rr & 7))*8);
        vv[i][1] = *(const s16x8*)(vp + ((4 + lg) ^ (rr & 7))*8);
      }
      #pragma unroll
      for (int qs = 0; qs < 2; ++qs){
        const int qqs = qq0 + qs*16;
        if (kt0 > qqs + 15 || kt0 + 63 < qqs - 127) continue;
        unsigned short* Pw = P[w][qs];
        #pragma unroll
        for (int ks2 = 0; ks2 < 2; ++ks2){
          s16x8 pb = *(const s16x8*)(Pw + lq*72 + ks2*32 + lg*8);
          #pragma unroll
          for (int i = 0; i < 4; ++i)
            yacc[qs][i] = MFMA16(vv[i][ks2], pb, yacc[qs][i]);
        }
      }
    }
    cur ^= 1;
  }
  #pragma unroll
  for (int qs = 0; qs < 2; ++qs){
    const float inv = 1.f / l_run[qs];
    unsigned short* yp = ys + ((size_t)n*512 + qq0 + qs*16 + lq)*512 + hh*64 + lg*4;
    #pragma unroll
    for (int i = 0; i < 4; ++i){
      u16x4 o;
      #pragma unroll
      for (int r = 0; r < 4; ++r) o[r] = f2bf(yacc[qs][i][r]*inv);
      *(u16x4*)(yp + i*16) = o;
    }
  }
}

extern "C" void kernel_launch(void* const* d_in, const int* in_sizes, int n_in,
                              void* d_out, int out_size, void* d_ws, size_t ws_size,
                              hipStream_t stream){
  const float* x     = (const float*)d_in[0];
  const float* Wqkv  = (const float*)d_in[1];
  const float* bqkv  = (const float*)d_in[2];
  const float* Wproj = (const float*)d_in[3];
  const float* bproj = (const float*)d_in[4];
  const float* relb  = (const float*)d_in[5];
  float* out = (float*)d_out;
  char* ws = (char*)d_ws;
  if (ws_size < (size_t)270532608) return;
  unsigned short* hbuf = (unsigned short*)(ws);                      // 64 MiB; reused as ys
  unsigned short* Qb   = (unsigned short*)(ws + (size_t)67108864);
  unsigned short* Kb   = (unsigned short*)(ws + (size_t)134217728);
  unsigned short* Vt   = (unsigned short*)(ws + (size_t)201326592);
  unsigned short* WqT  = (unsigned short*)(ws + (size_t)268435456);
  unsigned short* WpT  = (unsigned short*)(ws + (size_t)270008320);

  hipFuncSetAttribute(reinterpret_cast<const void*>(qkv_gemm256),
                      hipFuncAttributeMaxDynamicSharedMemorySize, 131072);
  hipFuncSetAttribute(reinterpret_cast<const void*>(proj_gemm256),
                      hipFuncAttributeMaxDynamicSharedMemorySize, 131072);

  hipLaunchKernelGGL(wt_prep,      dim3(256),  dim3(256), 0, stream, Wqkv, Wproj, WqT, WpT);
  hipLaunchKernelGGL(x_to_h,       dim3(8192), dim3(256), 0, stream, x, hbuf);
  hipLaunchKernelGGL(qkv_gemm256,  dim3(1536), dim3(512), 131072, stream, hbuf, WqT, bqkv, Qb, Kb, Vt);
  hipLaunchKernelGGL(attn_kernel,  dim3(4096), dim3(256), 0, stream, Qb, Kb, Vt, relb, hbuf);
  hipLaunchKernelGGL(proj_gemm256, dim3(512),  dim3(512), 131072, stream, hbuf, WpT, bproj, out);
}